// Round 1
// baseline (60.024 us; speedup 1.0000x reference)
//
#include <hip/hip_runtime.h>
#include <math.h>

// Problem constants (match reference)
static constexpr int Bn = 8;
static constexpr int Nn = 16;
static constexpr int Mn = 4;
static constexpr int Cn = 2;
static constexpr int HWn = 256 * 256;   // 65536
static constexpr int Sn = 8;            // segments per (b,n)
static constexpr int SEG = HWn / Sn;    // 8192
#define GAMMA_F 0.5f
#define MASS_F 0.25f
#define EPS_F 1e-8f

// Workspace layout (bytes):
//   inter_part: [B][N][S][M] floats = 4096 f @ 0      (16384 B)
//   ssum_part:  [B][N][S] floats    = 1024 f @ 16384  (4096 B)
//   gsum_part:  [B][S][M] uint      = 256 u  @ 20480  (1024 B)
// total 21504 B

__global__ __launch_bounds__(256) void inter_kernel(
    const float* __restrict__ sample, const int* __restrict__ gt,
    float* __restrict__ inter_part, float* __restrict__ ssum_part,
    unsigned int* __restrict__ gsum_part) {
  int blk = blockIdx.x;                 // ((b*N + n)*S + s)
  int s = blk % Sn;
  int bn = blk / Sn;
  int n = bn % Nn;
  int b = bn / Nn;

  const float* sp = sample + ((((size_t)b * Nn + n) * Cn + 1) * HWn) + (size_t)s * SEG;
  const int* gtb = gt + (size_t)b * Mn * HWn + (size_t)s * SEG;

  float ss = 0.f, im0 = 0.f, im1 = 0.f, im2 = 0.f, im3 = 0.f;
  unsigned int c0 = 0, c1 = 0, c2 = 0, c3 = 0;

  // SEG/4 = 2048 float4 elements over 256 threads -> 8 iters
  for (int i = threadIdx.x; i < SEG / 4; i += 256) {
    float4 x = reinterpret_cast<const float4*>(sp)[i];
    int4 g0 = reinterpret_cast<const int4*>(gtb + 0 * HWn)[i];
    int4 g1 = reinterpret_cast<const int4*>(gtb + 1 * HWn)[i];
    int4 g2 = reinterpret_cast<const int4*>(gtb + 2 * HWn)[i];
    int4 g3 = reinterpret_cast<const int4*>(gtb + 3 * HWn)[i];
    float xs[4] = {x.x, x.y, x.z, x.w};
    int m0[4] = {g0.x, g0.y, g0.z, g0.w};
    int m1[4] = {g1.x, g1.y, g1.z, g1.w};
    int m2[4] = {g2.x, g2.y, g2.z, g2.w};
    int m3[4] = {g3.x, g3.y, g3.z, g3.w};
#pragma unroll
    for (int e = 0; e < 4; ++e) {
      float v = xs[e];
      ss += v;
      bool b0 = (m0[e] == 1), b1 = (m1[e] == 1), b2 = (m2[e] == 1), b3 = (m3[e] == 1);
      im0 += b0 ? v : 0.0f;
      im1 += b1 ? v : 0.0f;
      im2 += b2 ? v : 0.0f;
      im3 += b3 ? v : 0.0f;
      c0 += b0; c1 += b1; c2 += b2; c3 += b3;
    }
  }

  // wave (64-lane) butterfly reduce
#pragma unroll
  for (int off = 32; off > 0; off >>= 1) {
    ss  += __shfl_down(ss, off);
    im0 += __shfl_down(im0, off);
    im1 += __shfl_down(im1, off);
    im2 += __shfl_down(im2, off);
    im3 += __shfl_down(im3, off);
    c0  += __shfl_down(c0, off);
    c1  += __shfl_down(c1, off);
    c2  += __shfl_down(c2, off);
    c3  += __shfl_down(c3, off);
  }

  __shared__ float sred[4][5];
  __shared__ unsigned int scnt[4][4];
  int lane = threadIdx.x & 63;
  int wv = threadIdx.x >> 6;
  if (lane == 0) {
    sred[wv][0] = ss; sred[wv][1] = im0; sred[wv][2] = im1;
    sred[wv][3] = im2; sred[wv][4] = im3;
    scnt[wv][0] = c0; scnt[wv][1] = c1; scnt[wv][2] = c2; scnt[wv][3] = c3;
  }
  __syncthreads();
  if (threadIdx.x == 0) {
    float t[5] = {0, 0, 0, 0, 0};
    for (int w = 0; w < 4; ++w)
      for (int v = 0; v < 5; ++v) t[v] += sred[w][v];
    ssum_part[(size_t)bn * Sn + s] = t[0];
    float* ip = inter_part + ((size_t)bn * Sn + s) * Mn;
    ip[0] = t[1]; ip[1] = t[2]; ip[2] = t[3]; ip[3] = t[4];
    if (n == 0) {
      unsigned int cc[4] = {0, 0, 0, 0};
      for (int w = 0; w < 4; ++w)
        for (int m = 0; m < 4; ++m) cc[m] += scnt[w][m];
      unsigned int* gp = gsum_part + ((size_t)b * Sn + s) * Mn;
      gp[0] = cc[0]; gp[1] = cc[1]; gp[2] = cc[2]; gp[3] = cc[3];
    }
  }
}

__global__ __launch_bounds__(256) void finish_kernel(
    const float* __restrict__ inter_part, const float* __restrict__ ssum_part,
    const unsigned int* __restrict__ gsum_part,
    const float* __restrict__ prob, const float* __restrict__ prob_gt,
    float* __restrict__ out) {
  __shared__ float s_inter[Bn * Nn * Mn];  // 512
  __shared__ float s_ssum[Bn * Nn];        // 128
  __shared__ float s_gsum[Bn * Mn];        // 32
  __shared__ float s_cost[Bn * Nn * Mn];   // 512
  __shared__ float s_seg[Bn], s_kl[Bn];
  int tid = threadIdx.x;

  for (int idx = tid; idx < Bn * Nn * Mn; idx += 256) {
    int bn = idx / Mn, m = idx % Mn;
    float acc = 0.f;
    for (int s = 0; s < Sn; ++s) acc += inter_part[((size_t)bn * Sn + s) * Mn + m];
    s_inter[idx] = acc;
  }
  for (int idx = tid; idx < Bn * Nn; idx += 256) {
    float acc = 0.f;
    for (int s = 0; s < Sn; ++s) acc += ssum_part[(size_t)idx * Sn + s];
    s_ssum[idx] = acc;
  }
  for (int idx = tid; idx < Bn * Mn; idx += 256) {
    int b = idx / Mn, m = idx % Mn;
    unsigned int acc = 0;
    for (int s = 0; s < Sn; ++s) acc += gsum_part[((size_t)b * Sn + s) * Mn + m];
    s_gsum[idx] = (float)acc;
  }
  __syncthreads();
  for (int idx = tid; idx < Bn * Nn * Mn; idx += 256) {
    int m = idx % Mn;
    int bn = idx / Mn;
    int b = bn / Nn;
    float inter = s_inter[idx];
    float uni = s_ssum[bn] + s_gsum[b * Mn + m] - inter;
    s_cost[idx] = 1.0f - (inter + 1.0f) / (uni + 1.0f);
  }
  __syncthreads();

  if (tid < Bn) {
    int b = tid;
    const float* cb = &s_cost[b * Nn * Mn];  // [n][m]
    float rowsums[Nn];
    float P[Nn][Mn];
    for (int n = 0; n < Nn; ++n) {
      rowsums[n] = 0.f;
      for (int m = 0; m < Mn; ++m) P[n][m] = 0.f;
    }
    // column order: argsort of per-column min (stable)
    float colmin[Mn];
    for (int m = 0; m < Mn; ++m) {
      float mn = cb[m];
      for (int n = 1; n < Nn; ++n) mn = fminf(mn, cb[n * Mn + m]);
      colmin[m] = mn;
    }
    int order[Mn];
    for (int m = 0; m < Mn; ++m) order[m] = m;
    for (int a = 1; a < Mn; ++a) {
      int key = order[a];
      float kv = colmin[key];
      int c = a - 1;
      while (c >= 0 && colmin[order[c]] > kv) { order[c + 1] = order[c]; --c; }
      order[c + 1] = key;
    }
    // greedy fill per column in sorted order
    for (int k = 0; k < Mn; ++k) {
      int i = order[k];
      int ordj[Nn];
      for (int n = 0; n < Nn; ++n) ordj[n] = n;
      for (int a = 1; a < Nn; ++a) {  // stable insertion sort by cb[:,i]
        int key = ordj[a];
        float kv = cb[key * Mn + i];
        int c = a - 1;
        while (c >= 0 && cb[ordj[c] * Mn + i] > kv) { ordj[c + 1] = ordj[c]; --c; }
        ordj[c + 1] = key;
      }
      float excl = 0.0f;
      for (int t = 0; t < Nn; ++t) {
        int j = ordj[t];
        float cap = GAMMA_F - rowsums[j];
        float a = MASS_F - excl;
        a = fminf(fmaxf(a, 0.0f), cap);
        P[j][i] = a;
        rowsums[j] += a;
        excl += cap;
      }
    }
    // losses
    float seg = 0.0f, kl = 0.0f;
    for (int n = 0; n < Nn; ++n) {
      float target = 0.0f;
      for (int m = 0; m < Mn; ++m) {
        float p = P[n][m] * prob_gt[b * Mn + m] * (float)Mn;
        seg += p * cb[n * Mn + m];
        target += p;
      }
      if (target > 0.0f)
        kl += target * (logf(target) - logf(prob[b * Nn + n] + EPS_F));
    }
    s_seg[b] = seg;
    s_kl[b] = kl;
  }
  __syncthreads();
  if (tid == 0) {
    float seg = 0.f, kl = 0.f;
    for (int b = 0; b < Bn; ++b) { seg += s_seg[b]; kl += s_kl[b]; }
    seg /= (float)Bn;
    kl /= (float)(Bn * Nn);
    out[0] = seg + 1.0f * kl;  // loss (BETA = 1)
    out[1] = seg;              // seg_loss
    out[2] = kl;               // kl
  }
}

extern "C" void kernel_launch(void* const* d_in, const int* in_sizes, int n_in,
                              void* d_out, int out_size, void* d_ws, size_t ws_size,
                              hipStream_t stream) {
  const int* gt = (const int*)d_in[0];          // (B,M,H,W) int32
  const float* sample = (const float*)d_in[1];  // (B,N,C,H,W) f32
  const float* prob = (const float*)d_in[2];    // (B,N)
  const float* prob_gt = (const float*)d_in[3]; // (B,M)
  float* out = (float*)d_out;

  char* ws = (char*)d_ws;
  float* inter_part = (float*)(ws + 0);
  float* ssum_part = (float*)(ws + 16384);
  unsigned int* gsum_part = (unsigned int*)(ws + 20480);

  inter_kernel<<<Bn * Nn * Sn, 256, 0, stream>>>(sample, gt, inter_part, ssum_part, gsum_part);
  finish_kernel<<<1, 256, 0, stream>>>(inter_part, ssum_part, gsum_part, prob, prob_gt, out);
}

// Round 2
// 20.681 us; speedup vs baseline: 2.9024x; 2.9024x over previous
//
#include <hip/hip_runtime.h>
#include <math.h>

// Problem constants (match reference)
static constexpr int Bn = 8;
static constexpr int Nn = 16;
static constexpr int Mn = 4;
static constexpr int Cn = 2;
static constexpr int HWn = 256 * 256;   // 65536
static constexpr int Sn = 8;            // segments per (b,n)
static constexpr int SEG = HWn / Sn;    // 8192
#define GAMMA_F 0.5f
#define MASS_F 0.25f
#define EPS_F 1e-8f

// Workspace layout (bytes):
//   inter_part: [B][N][S][M] floats = 4096 f @ 0      (16384 B)
//   ssum_part:  [B][N][S] floats    = 1024 f @ 16384  (4096 B)
//   gsum_part:  [B][S][M] uint      = 256 u  @ 20480  (1024 B)

__global__ __launch_bounds__(256) void inter_kernel(
    const float* __restrict__ sample, const int* __restrict__ gt,
    float* __restrict__ inter_part, float* __restrict__ ssum_part,
    unsigned int* __restrict__ gsum_part) {
  int blk = blockIdx.x;                 // ((b*N + n)*S + s)
  int s = blk % Sn;
  int bn = blk / Sn;
  int n = bn % Nn;
  int b = bn / Nn;

  const float* sp = sample + ((((size_t)b * Nn + n) * Cn + 1) * HWn) + (size_t)s * SEG;
  const int* gtb = gt + (size_t)b * Mn * HWn + (size_t)s * SEG;

  float ss = 0.f, im0 = 0.f, im1 = 0.f, im2 = 0.f, im3 = 0.f;
  unsigned int c0 = 0, c1 = 0, c2 = 0, c3 = 0;

  for (int i = threadIdx.x; i < SEG / 4; i += 256) {
    float4 x = reinterpret_cast<const float4*>(sp)[i];
    int4 g0 = reinterpret_cast<const int4*>(gtb + 0 * HWn)[i];
    int4 g1 = reinterpret_cast<const int4*>(gtb + 1 * HWn)[i];
    int4 g2 = reinterpret_cast<const int4*>(gtb + 2 * HWn)[i];
    int4 g3 = reinterpret_cast<const int4*>(gtb + 3 * HWn)[i];
    float xs[4] = {x.x, x.y, x.z, x.w};
    int m0[4] = {g0.x, g0.y, g0.z, g0.w};
    int m1[4] = {g1.x, g1.y, g1.z, g1.w};
    int m2[4] = {g2.x, g2.y, g2.z, g2.w};
    int m3[4] = {g3.x, g3.y, g3.z, g3.w};
#pragma unroll
    for (int e = 0; e < 4; ++e) {
      float v = xs[e];
      ss += v;
      bool b0 = (m0[e] == 1), b1 = (m1[e] == 1), b2 = (m2[e] == 1), b3 = (m3[e] == 1);
      im0 += b0 ? v : 0.0f;
      im1 += b1 ? v : 0.0f;
      im2 += b2 ? v : 0.0f;
      im3 += b3 ? v : 0.0f;
      c0 += b0; c1 += b1; c2 += b2; c3 += b3;
    }
  }

#pragma unroll
  for (int off = 32; off > 0; off >>= 1) {
    ss  += __shfl_down(ss, off);
    im0 += __shfl_down(im0, off);
    im1 += __shfl_down(im1, off);
    im2 += __shfl_down(im2, off);
    im3 += __shfl_down(im3, off);
    c0  += __shfl_down(c0, off);
    c1  += __shfl_down(c1, off);
    c2  += __shfl_down(c2, off);
    c3  += __shfl_down(c3, off);
  }

  __shared__ float sred[4][5];
  __shared__ unsigned int scnt[4][4];
  int lane = threadIdx.x & 63;
  int wv = threadIdx.x >> 6;
  if (lane == 0) {
    sred[wv][0] = ss; sred[wv][1] = im0; sred[wv][2] = im1;
    sred[wv][3] = im2; sred[wv][4] = im3;
    scnt[wv][0] = c0; scnt[wv][1] = c1; scnt[wv][2] = c2; scnt[wv][3] = c3;
  }
  __syncthreads();
  if (threadIdx.x == 0) {
    float t[5] = {0, 0, 0, 0, 0};
    for (int w = 0; w < 4; ++w)
      for (int v = 0; v < 5; ++v) t[v] += sred[w][v];
    ssum_part[(size_t)bn * Sn + s] = t[0];
    float* ip = inter_part + ((size_t)bn * Sn + s) * Mn;
    ip[0] = t[1]; ip[1] = t[2]; ip[2] = t[3]; ip[3] = t[4];
    if (n == 0) {
      unsigned int cc[4] = {0, 0, 0, 0};
      for (int w = 0; w < 4; ++w)
        for (int m = 0; m < 4; ++m) cc[m] += scnt[w][m];
      unsigned int* gp = gsum_part + ((size_t)b * Sn + s) * Mn;
      gp[0] = cc[0]; gp[1] = cc[1]; gp[2] = cc[2]; gp[3] = cc[3];
    }
  }
}

// Coupling + losses, fully register/shuffle based: one lane per (b,n) row.
// No runtime-indexed private arrays -> no scratch.
__global__ __launch_bounds__(256) void finish_kernel(
    const float* __restrict__ inter_part, const float* __restrict__ ssum_part,
    const unsigned int* __restrict__ gsum_part,
    const float* __restrict__ prob, const float* __restrict__ prob_gt,
    float* __restrict__ out) {
  __shared__ float s_cost[Bn * Nn * Mn];   // [b][n][m], 512 f
  __shared__ float s_ssum[Bn * Nn];
  __shared__ float s_gsum[Bn * Mn];
  __shared__ float s_red[8];               // per-wave {seg, kl}
  int tid = threadIdx.x;

  // phase 1a: row sums / gt sums
  if (tid < Bn * Nn) {
    float acc = 0.f;
    for (int s = 0; s < Sn; ++s) acc += ssum_part[(size_t)tid * Sn + s];
    s_ssum[tid] = acc;
  }
  if (tid >= 128 && tid < 128 + Bn * Mn) {
    int idx = tid - 128;
    int b = idx / Mn, m = idx % Mn;
    unsigned int acc = 0;
    for (int s = 0; s < Sn; ++s) acc += gsum_part[((size_t)b * Sn + s) * Mn + m];
    s_gsum[idx] = (float)acc;
  }
  __syncthreads();

  // phase 1b: cost
  for (int idx = tid; idx < Bn * Nn * Mn; idx += 256) {
    int m = idx % Mn;
    int bn = idx / Mn;
    int b = bn / Nn;
    float acc = 0.f;
    for (int s = 0; s < Sn; ++s) acc += inter_part[((size_t)bn * Sn + s) * Mn + m];
    float uni = s_ssum[bn] + s_gsum[b * Mn + m] - acc;
    s_cost[idx] = 1.0f - (acc + 1.0f) / (uni + 1.0f);
  }
  __syncthreads();

  // phase 2: coupling, lane per (b,n). tid<128 -> waves 0,1 (wave-uniform branch).
  float seg_part = 0.f, kl_part = 0.f;
  if (tid < Bn * Nn) {
    int b = tid >> 4;
    int n = tid & 15;
    int base = (tid & 63) & ~15;  // start lane of this 16-lane group within the wave

    float4 cv = *reinterpret_cast<const float4*>(&s_cost[tid * Mn]);
    float cc0 = cv.x, cc1 = cv.y, cc2 = cv.z, cc3 = cv.w;
    float pg0 = prob_gt[b * Mn + 0], pg1 = prob_gt[b * Mn + 1];
    float pg2 = prob_gt[b * Mn + 2], pg3 = prob_gt[b * Mn + 3];

    // column minima via 16-lane butterfly (all lanes end with the min)
    float m0 = cc0, m1 = cc1, m2 = cc2, m3 = cc3;
#pragma unroll
    for (int off = 1; off < 16; off <<= 1) {
      m0 = fminf(m0, __shfl_xor(m0, off));
      m1 = fminf(m1, __shfl_xor(m1, off));
      m2 = fminf(m2, __shfl_xor(m2, off));
      m3 = fminf(m3, __shfl_xor(m3, off));
    }
    // stable ascending ranks of the 4 column minima
    int r0 = (m1 < m0) + (m2 < m0) + (m3 < m0);
    int r1 = (m0 <= m1) + (m2 < m1) + (m3 < m1);
    int r2 = (m0 <= m2) + (m1 <= m2) + (m3 < m2);
    int r3 = (m0 <= m3) + (m1 <= m3) + (m2 <= m3);

    float rowsum = 0.f;
    float target = 0.f;
#pragma unroll
    for (int k = 0; k < Mn; ++k) {
      int i = (r0 == k) ? 0 : (r1 == k) ? 1 : (r2 == k) ? 2 : 3;
      float v = (i == 0) ? cc0 : (i == 1) ? cc1 : (i == 2) ? cc2 : cc3;
      float pg = (i == 0) ? pg0 : (i == 1) ? pg1 : (i == 2) ? pg2 : pg3;
      float cap = GAMMA_F - rowsum;
      // excl = sum of caps of rows that stably-sort before this row on column i
      float excl = 0.f;
#pragma unroll 4
      for (int j = 0; j < Nn; ++j) {
        float vj = __shfl(v, base + j);
        float capj = __shfl(cap, base + j);
        bool pred = (vj < v) || (vj == v && j < n);
        excl += pred ? capj : 0.f;
      }
      float a = fminf(fmaxf(MASS_F - excl, 0.f), cap);
      rowsum += a;
      float p = a * pg * (float)Mn;
      seg_part += p * v;
      target += p;
    }
    kl_part = (target > 0.f)
                  ? target * (logf(target) - logf(prob[tid] + EPS_F))
                  : 0.f;
  }

  // phase 3: global reduction of seg/kl
#pragma unroll
  for (int off = 32; off > 0; off >>= 1) {
    seg_part += __shfl_down(seg_part, off);
    kl_part += __shfl_down(kl_part, off);
  }
  int lane = tid & 63, wv = tid >> 6;
  if (lane == 0) { s_red[wv * 2] = seg_part; s_red[wv * 2 + 1] = kl_part; }
  __syncthreads();
  if (tid == 0) {
    float seg = 0.f, kl = 0.f;
    for (int w = 0; w < 4; ++w) { seg += s_red[w * 2]; kl += s_red[w * 2 + 1]; }
    seg /= (float)Bn;
    kl /= (float)(Bn * Nn);
    out[0] = seg + 1.0f * kl;  // BETA = 1
    out[1] = seg;
    out[2] = kl;
  }
}

extern "C" void kernel_launch(void* const* d_in, const int* in_sizes, int n_in,
                              void* d_out, int out_size, void* d_ws, size_t ws_size,
                              hipStream_t stream) {
  const int* gt = (const int*)d_in[0];          // (B,M,H,W) int32
  const float* sample = (const float*)d_in[1];  // (B,N,C,H,W) f32
  const float* prob = (const float*)d_in[2];    // (B,N)
  const float* prob_gt = (const float*)d_in[3]; // (B,M)
  float* out = (float*)d_out;

  char* ws = (char*)d_ws;
  float* inter_part = (float*)(ws + 0);
  float* ssum_part = (float*)(ws + 16384);
  unsigned int* gsum_part = (unsigned int*)(ws + 20480);

  inter_kernel<<<Bn * Nn * Sn, 256, 0, stream>>>(sample, gt, inter_part, ssum_part, gsum_part);
  finish_kernel<<<1, 256, 0, stream>>>(inter_part, ssum_part, gsum_part, prob, prob_gt, out);
}